// Round 1
// baseline (400.532 us; speedup 1.0000x reference)
//
#include <hip/hip_runtime.h>

#define ENC 50
#define NT 20
#define TEMPC 5.0f
#define HSTRIDE 72   // bf16 elems per batch row in LDS: 144B, 16B-aligned, odd dword stride vs banks

typedef __attribute__((ext_vector_type(8))) short bf16x8;
typedef __attribute__((ext_vector_type(4))) float f32x4;

__device__ __forceinline__ unsigned short f2bf(float x) {
  union { float f; unsigned u; } cv; cv.f = x;
  unsigned u = cv.u;
  u += 0x7FFFu + ((u >> 16) & 1u);   // RNE
  return (unsigned short)(u >> 16);
}

__device__ __forceinline__ float fsig(float x) {
  float e = __builtin_amdgcn_exp2f(x * -1.4426950408889634f); // exp(-x)
  return __builtin_amdgcn_rcpf(1.0f + e);
}
__device__ __forceinline__ float ftanh(float x) {
  float e = __builtin_amdgcn_exp2f(x * 2.8853900817779268f);  // exp(2x)
  return 1.0f - 2.0f * __builtin_amdgcn_rcpf(e + 1.0f);
}

// Build permuted-transposed bf16 A-fragments of Utilde = [U_lstm; W_lstm; b_lstm] (53x200 -> 64x208 padded)
// perm row = 16*(f>>2) + 4*(f&3) + gate  (f = feature 0..51, gate: 0=i 1=f 2=g 3=o)
// frag (m,kt): lane l holds A[16m + (l&15)][32kt + 8*(l>>4) + e], e=0..7
__global__ void idm_prep(const float* __restrict__ U, const float* __restrict__ Wl,
                         const float* __restrict__ bl, const float* __restrict__ Wa,
                         const float* __restrict__ ba, const float* __restrict__ Wn,
                         const float* __restrict__ bn,
                         unsigned short* __restrict__ Afrag, float* __restrict__ wcomb) {
  int tid = blockIdx.x * blockDim.x + threadIdx.x;
  for (int idx = tid; idx < 26 * 64; idx += blockDim.x * gridDim.x) {
    int frag = idx >> 6, lane = idx & 63;
    int m = frag >> 1, kt = frag & 1;
    int sub = lane & 15;
    int kbase = 32 * kt + 8 * (lane >> 4);
    int p = sub >> 2, q = sub & 3;
    int f = 4 * m + p;
    unsigned short o[8];
#pragma unroll
    for (int e = 0; e < 8; ++e) {
      int k = kbase + e;
      float val = 0.f;
      if (f < ENC) {
        int col = q * ENC + f;
        if (k < ENC)            val = U[k * 4 * ENC + col];
        else if (k == ENC)      val = Wl[col];
        else if (k == ENC + 1)  val = Wl[4 * ENC + col];
        else if (k == ENC + 2)  val = bl[col];
      }
      o[e] = f2bf(val);
    }
#pragma unroll
    for (int e = 0; e < 8; ++e) Afrag[idx * 8 + e] = o[e];
  }
  if (tid < 52) {
    float s = 0.f;
    if (tid < ENC) { for (int j = 0; j < ENC; ++j) s += Wa[tid * ENC + j] * Wn[j]; }
    wcomb[tid] = s;
  }
  if (tid == 52) {
    float s = bn[0];
    for (int j = 0; j < ENC; ++j) s += ba[j] * Wn[j];
    wcomb[52] = s;
  }
}

template <int PRE>
__global__ __launch_bounds__(256, 2) void idm_main(
    const float* __restrict__ s_in, const float* __restrict__ zin,
    const float* __restrict__ dvp, const float* __restrict__ tgp,
    const float* __restrict__ jxp, const float* __restrict__ map,
    const float* __restrict__ mip, const float* __restrict__ h0,
    const float* __restrict__ c0,
    const unsigned short* __restrict__ Afrag, const float* __restrict__ wcomb,
    const float* __restrict__ U, const float* __restrict__ Wl, const float* __restrict__ bl,
    const float* __restrict__ Wa, const float* __restrict__ ba,
    const float* __restrict__ Wn, const float* __restrict__ bn,
    float* __restrict__ out_act, float* __restrict__ out_att, int Btot) {
  __shared__ __align__(16) unsigned short hlds[4 * 16 * HSTRIDE];
  __shared__ float wcl[64];
  const int tid = threadIdx.x;
  const int wid = tid >> 6, lane = tid & 63;
  const int v = lane & 15, p = lane >> 4;
  int b = blockIdx.x * 64 + wid * 16 + v;
  if (b >= Btot) b = Btot - 1;   // benign duplicate work

  bf16x8 A[13][2];
  float wc[13], bcomb;
  if (PRE) {
#pragma unroll
    for (int m = 0; m < 13; ++m) {
      A[m][0] = ((const bf16x8*)Afrag)[(2 * m) * 64 + lane];
      A[m][1] = ((const bf16x8*)Afrag)[(2 * m + 1) * 64 + lane];
    }
#pragma unroll
    for (int m = 0; m < 13; ++m) { int f = 4 * m + p; wc[m] = (f < ENC) ? wcomb[f] : 0.f; }
    bcomb = wcomb[52];
  } else {
    if (tid < 52) {
      float s = 0.f;
      if (tid < ENC) { for (int j = 0; j < ENC; ++j) s += Wa[tid * ENC + j] * Wn[j]; }
      wcl[tid] = s;
    }
    if (tid == 52) {
      float s = bn[0];
      for (int j = 0; j < ENC; ++j) s += ba[j] * Wn[j];
      wcl[52] = s;
    }
    __syncthreads();
#pragma unroll
    for (int m = 0; m < 13; ++m) {
#pragma unroll
      for (int kt = 0; kt < 2; ++kt) {
        const int pp = v >> 2, q = v & 3;
        const int fb = 4 * m + pp;
        const int kbase = 32 * kt + 8 * p;
        bf16x8 a;
#pragma unroll
        for (int e = 0; e < 8; ++e) {
          int k = kbase + e;
          float val = 0.f;
          if (fb < ENC) {
            int col = q * ENC + fb;
            if (k < ENC)            val = U[k * 4 * ENC + col];
            else if (k == ENC)      val = Wl[col];
            else if (k == ENC + 1)  val = Wl[4 * ENC + col];
            else if (k == ENC + 2)  val = bl[col];
          }
          a[e] = (short)f2bf(val);
        }
        A[m][kt] = a;
      }
    }
#pragma unroll
    for (int m = 0; m < 13; ++m) { int f = 4 * m + p; wc[m] = (f < ENC) ? wcl[f] : 0.f; }
    bcomb = wcl[52];
  }

  // per-row params (p-redundant; cached)
  const float amax = map[b], amin = mip[b];
  const float tgap = tgp[b], jamx = jxp[b];
  const float inv_dv = __builtin_amdgcn_rcpf(dvp[b]);
  const float inv2s = 0.5f * __builtin_amdgcn_rsqf(amax * amin);

  // c state in registers: feature f = 4m+p of batch b
  float c[13];
#pragma unroll
  for (int m = 0; m < 13; ++m) {
    int f = 4 * m + p;
    c[m] = (f < ENC) ? c0[(size_t)b * ENC + f] : 0.f;
  }

  // init h-tilde LDS region for this wave: rows = 16 batches, cols = [h(50), z0, z1, 1, 0-pad]
  unsigned short* hl = &hlds[wid * 16 * HSTRIDE];
  for (int i = lane; i < 16 * HSTRIDE / 2; i += 64) ((unsigned*)hl)[i] = 0u;
#pragma unroll
  for (int m = 0; m < 13; ++m) {
    int f = 4 * m + p;
    if (f < ENC) hl[v * HSTRIDE + f] = f2bf(h0[(size_t)b * ENC + f]);
  }
  if (p == 0) {
    hl[v * HSTRIDE + 50] = f2bf(zin[(size_t)b * 2 + 0]);
    hl[v * HSTRIDE + 51] = f2bf(zin[(size_t)b * 2 + 1]);
    hl[v * HSTRIDE + 52] = (unsigned short)0x3F80; // bf16(1.0)
  }

  const float* srow = s_in + (size_t)b * (NT * 7);
  const size_t ob = (size_t)b * NT;
  const bf16x8* hv = (const bf16x8*)hl;

#pragma unroll 1
  for (int t = 0; t < NT; ++t) {
    // B-fragments: lane reads h~[batch=v][k = 8p..8p+7 (+32)]
    bf16x8 B0 = hv[v * 9 + p];
    bf16x8 B1 = hv[v * 9 + 4 + p];
    f32x4 acc[13];
#pragma unroll
    for (int m = 0; m < 13; ++m) {
      f32x4 t0 = {0.f, 0.f, 0.f, 0.f};
      t0 = __builtin_amdgcn_mfma_f32_16x16x32_bf16(A[m][0], B0, t0, 0, 0, 0);
      acc[m] = __builtin_amdgcn_mfma_f32_16x16x32_bf16(A[m][1], B1, t0, 0, 0, 0);
    }
    // lane-local LSTM cell: acc[m] = {i,f,g,o} of feature 4m+p
    float att_dot = 0.f;
#pragma unroll
    for (int m = 0; m < 13; ++m) {
      float sgi = fsig(acc[m][0]);
      float sgf = fsig(acc[m][1]);
      float tgg = ftanh(acc[m][2]);
      float sgo = fsig(acc[m][3]);
      float cn = sgf * c[m] + sgi * tgg;
      c[m] = cn;
      float hn = sgo * ftanh(cn);
      att_dot += hn * wc[m];           // wc padded 0 for f>=50
      int f = 4 * m + p;
      if (f < ENC) hl[v * HSTRIDE + f] = f2bf(hn);
    }
    att_dot += __shfl_xor(att_dot, 16, 64);
    att_dot += __shfl_xor(att_dot, 32, 64);
    float att = fsig(TEMPC * (att_dot + bcomb));

    // IDM (per-row, p-redundant)
    const float* sp = srow + t * 7;
    float vel = sp[0], dvl = sp[2], dxl = sp[3], dvm = sp[5], dxm = sp[6];
    float r = vel * inv_dv;
    float r2 = r * r;
    float r4 = r2 * r2;
    float base = jamx + tgap * vel;
    float gl = (base + vel * dvl * inv2s) * __builtin_amdgcn_rcpf(dxl);
    float fl = amax * (1.f - r4 - gl * gl);
    fl = fminf(fmaxf(fl, -3.5f), 3.5f);
    float gm = (base + vel * dvm * inv2s) * __builtin_amdgcn_rcpf(dxm);
    float fm = amax * (1.f - r4 - gm * gm);
    fm = fminf(fmaxf(fm, -3.5f), 3.5f);
    float act = att * fl + (1.f - att) * fm;
    if (p == 0) {
      out_act[ob + t] = act;
      out_att[ob + t] = att;
    }
  }
}

extern "C" void kernel_launch(void* const* d_in, const int* in_sizes, int n_in,
                              void* d_out, int out_size, void* d_ws, size_t ws_size,
                              hipStream_t stream) {
  const float* s   = (const float*)d_in[0];
  const float* z   = (const float*)d_in[1];
  const float* dv  = (const float*)d_in[2];
  const float* tg  = (const float*)d_in[3];
  const float* jx  = (const float*)d_in[4];
  const float* ma  = (const float*)d_in[5];
  const float* mi  = (const float*)d_in[6];
  const float* h0  = (const float*)d_in[7];
  const float* c0  = (const float*)d_in[8];
  const float* Wl  = (const float*)d_in[9];
  const float* Ul  = (const float*)d_in[10];
  const float* bl  = (const float*)d_in[11];
  const float* Wa  = (const float*)d_in[12];
  const float* ba  = (const float*)d_in[13];
  const float* Wn  = (const float*)d_in[14];
  const float* bn  = (const float*)d_in[15];
  const int B = in_sizes[2];
  float* out_act = (float*)d_out;
  float* out_att = out_act + (size_t)B * NT;
  const int grid = (B + 63) / 64;
  const size_t need = (size_t)26 * 64 * 8 * sizeof(unsigned short) + 64 * sizeof(float);
  if (d_ws && ws_size >= need) {
    unsigned short* Af = (unsigned short*)d_ws;
    float* wcb = (float*)(Af + 26 * 64 * 8);
    idm_prep<<<1, 256, 0, stream>>>(Ul, Wl, bl, Wa, ba, Wn, bn, Af, wcb);
    idm_main<1><<<grid, 256, 0, stream>>>(s, z, dv, tg, jx, ma, mi, h0, c0, Af, wcb,
                                          Ul, Wl, bl, Wa, ba, Wn, bn, out_act, out_att, B);
  } else {
    idm_main<0><<<grid, 256, 0, stream>>>(s, z, dv, tg, jx, ma, mi, h0, c0, nullptr, nullptr,
                                          Ul, Wl, bl, Wa, ba, Wn, bn, out_act, out_att, B);
  }
}